// Round 1
// baseline (868.255 us; speedup 1.0000x reference)
//
#include <hip/hip_runtime.h>
#include <math.h>

// CrossViewSwapAttention forward, fp32, correctness-first round.
// B=2 N=6 H=W=64 FH=32 FW=88 DIM=128 HEADS=4 DH=32 QW=8x8 KW=4x11
// L=64 windows, stage1: 384 q x 264 k per window; stage2: 64 q x 264 k.

__device__ __forceinline__ size_t remap_kv(int tok, int mode){
  // tok = bn*2816 + i*88 + j  ->  KP/VP row ((b*64+l)*264 + t)
  int bn = tok / 2816; int p = tok - bn*2816;
  int b = bn / 6, n = bn - b*6;
  int i = p / 88, j = p - i*88;
  int l, t;
  if (mode == 1){            // stage 1: _win(k, 4, 11)
    int jw = j / 11;
    l = (i >> 2)*8 + jw;
    t = n*44 + (i & 3)*11 + (j - jw*11);
  } else {                   // stage 2: _gridwin(k, 4, 11)
    l = (i & 7)*8 + (j & 7);
    t = n*44 + (i >> 3)*11 + (j >> 3);
  }
  return (size_t)((b*64 + l)*264 + t);
}

// c_embed[bn][o] = sum_c W_cam[o][c] * E_inv[bn][c][3]
__global__ __launch_bounds__(128) void k_cembed(const float* __restrict__ Einv,
                                                const float* __restrict__ Wcam,
                                                float* __restrict__ CE){
  int bn = blockIdx.x, o = threadIdx.x;
  const float* E = Einv + bn*16;
  const float* W = Wcam + o*4;
  CE[bn*128 + o] = W[0]*E[3] + W[1]*E[7] + W[2]*E[11] + W[3]*E[15];
}

// img_embed (normalized over channel) -> K1 (channel-last, (bn,p,c))
__global__ __launch_bounds__(128) void k_geom(const float* __restrict__ Iinv,
                                              const float* __restrict__ Einv,
                                              const float* __restrict__ Wimg,
                                              const float* __restrict__ CE,
                                              float* __restrict__ K1){
  int tile = blockIdx.x;               // bn*352 + tp  (8 pixels per block)
  int bn = tile / 352; int p0 = (tile - bn*352)*8;
  int xid = threadIdx.x >> 4, part = threadIdx.x & 15;
  int p = p0 + xid;
  int i = p / 88, j = p - i*88;
  float xs = (float)j * (480.0f/87.0f);
  float ys = (float)i * (224.0f/31.0f);
  const float* I = Iinv + bn*9;
  const float* E = Einv + bn*16;
  float c0 = I[0]*xs + I[1]*ys + I[2];
  float c1 = I[3]*xs + I[4]*ys + I[5];
  float c2 = I[6]*xs + I[7]*ys + I[8];
  float d0 = E[0]*c0 + E[1]*c1 + E[2]*c2 + E[3];
  float d1 = E[4]*c0 + E[5]*c1 + E[6]*c2 + E[7];
  float d2 = E[8]*c0 + E[9]*c1 + E[10]*c2 + E[11];
  float d3 = E[12]*c0 + E[13]*c1 + E[14]*c2 + E[15];
  float v[8]; float sq = 0.f;
  #pragma unroll
  for (int k=0;k<8;k++){
    int o = part*8 + k;
    const float* W = Wimg + o*4;
    float de = W[0]*d0 + W[1]*d1 + W[2]*d2 + W[3]*d3;
    float vv = de - CE[bn*128 + o];
    v[k] = vv; sq = fmaf(vv, vv, sq);
  }
  #pragma unroll
  for (int off=8; off>0; off>>=1) sq += __shfl_xor(sq, off, 16);
  float rn = 1.0f / fmaxf(sqrtf(sq), 1e-12f);
  float* dst = K1 + (size_t)(bn*2816 + p)*128 + part*8;
  #pragma unroll
  for (int k=0;k<8;k++) dst[k] = v[k]*rn;
}

// K1 += conv_fp(feat), V1 = conv_fl(feat)   (BN eval + relu + 1x1 conv)
__global__ __launch_bounds__(128) void k_conv(const float* __restrict__ feat,
    const float* __restrict__ gfl, const float* __restrict__ bfl, const float* __restrict__ Wfl,
    const float* __restrict__ gfp, const float* __restrict__ bfp, const float* __restrict__ Wfp,
    float* __restrict__ K1, float* __restrict__ V1){
  __shared__ float sfp[128][8];
  __shared__ float sfl[128][8];
  int tile = blockIdx.x;
  int bn = tile / 352; int p0 = (tile - bn*352)*8;
  int c = threadIdx.x;
  const float rsq = rsqrtf(1.0f + 1e-5f);
  const float* fp = feat + ((size_t)bn*128 + c)*2816 + p0;
  float4 a0 = *(const float4*)fp;
  float4 a1 = *(const float4*)(fp + 4);
  float vals[8] = {a0.x,a0.y,a0.z,a0.w,a1.x,a1.y,a1.z,a1.w};
  float gl = gfl[c], bl = bfl[c], gp = gfp[c], bp = bfp[c];
  #pragma unroll
  for (int x=0;x<8;x++){
    float t = vals[x]*rsq;
    sfl[c][x] = fmaxf(fmaf(t, gl, bl), 0.f);
    sfp[c][x] = fmaxf(fmaf(t, gp, bp), 0.f);
  }
  __syncthreads();
  int o = threadIdx.x;
  float ak[8] = {0,0,0,0,0,0,0,0};
  float av[8] = {0,0,0,0,0,0,0,0};
  const float* wkp = Wfp + o*128;
  const float* wlp = Wfl + o*128;
  #pragma unroll 4
  for (int cc=0; cc<128; cc++){
    float wk = wkp[cc], wl = wlp[cc];
    #pragma unroll
    for (int x=0;x<8;x++){
      ak[x] = fmaf(wk, sfp[cc][x], ak[x]);
      av[x] = fmaf(wl, sfl[cc][x], av[x]);
    }
  }
  float* kdst = K1 + (size_t)(bn*2816 + p0)*128 + o;
  float* vdst = V1 + (size_t)(bn*2816 + p0)*128 + o;
  #pragma unroll
  for (int x=0;x<8;x++){
    kdst[x*128] += ak[x];
    vdst[x*128]  = av[x];
  }
}

// query = normalize(w_embed - c_embed) + x ; written in stage-1 window-token order
__global__ __launch_bounds__(128) void k_bevq(const float* __restrict__ gridp,
    const float* __restrict__ Wbev, const float* __restrict__ bbev,
    const float* __restrict__ CE, const float* __restrict__ x,
    float* __restrict__ Q){
  int tile = blockIdx.x;               // bn*512 + tp (8 pixels per block)
  int bn = tile >> 9; int pp0 = (tile & 511) << 3;
  int b = bn / 6, n = bn - b*6;
  int xid = threadIdx.x >> 4, part = threadIdx.x & 15;
  int pix = pp0 + xid;
  int h = pix >> 6, w = pix & 63;
  float g0 = gridp[pix], g1 = gridp[4096 + pix];
  float v[8]; float sq = 0.f;
  #pragma unroll
  for (int k=0;k<8;k++){
    int o = part*8 + k;
    float we = Wbev[o*2]*g0 + Wbev[o*2+1]*g1 + bbev[o];
    float vv = we - CE[bn*128 + o];
    v[k] = vv; sq = fmaf(vv, vv, sq);
  }
  #pragma unroll
  for (int off=8; off>0; off>>=1) sq += __shfl_xor(sq, off, 16);
  float rn = 1.0f / fmaxf(sqrtf(sq), 1e-12f);
  int l = (h>>3)*8 + (w>>3);
  int t = n*64 + (h&7)*8 + (w&7);
  size_t row = (size_t)((b*64 + l)*384 + t);
  const float* xp = x + ((size_t)b*128)*4096 + pix;
  float* dst = Q + row*128 + part*8;
  #pragma unroll
  for (int k=0;k<8;k++){
    int o = part*8 + k;
    dst[k] = fmaf(v[k], rn, xp[(size_t)o*4096]);
  }
}

// generic (optional LN) + 128x128 GEMM + bias (+ optional skip), scatter rows.
// grid = 1024: blockIdx&1 selects output-channel half (W half in LDS, 32KB).
// 32 tokens per chunk, each thread computes a 4(out) x 4(token) tile.
__global__ __launch_bounds__(128) void k_lngemm(const float* __restrict__ X,
    const float* __restrict__ lg, const float* __restrict__ lb,
    const float* __restrict__ W, const float* __restrict__ bias,
    float* __restrict__ OUT, int M, int outmode, int do_ln, int skip_mode,
    const float* __restrict__ skipp){
  __shared__ float sW[8192];     // [c][64] for this half
  __shared__ float sln[4096];    // [c][32]
  __shared__ float sg[128], sb[128], sbias[64];
  int colh = blockIdx.x & 1;
  int cb = blockIdx.x >> 1;
  for (int idx = threadIdx.x; idx < 8192; idx += 128){
    int c = idx >> 6, oo = idx & 63;
    sW[idx] = W[(c<<7) + (colh<<6) + oo];
  }
  if (do_ln){ sg[threadIdx.x] = lg[threadIdx.x]; sb[threadIdx.x] = lb[threadIdx.x]; }
  if (threadIdx.x < 64) sbias[threadIdx.x] = bias[(colh<<6) + threadIdx.x];
  const int xid = threadIdx.x >> 2, part = threadIdx.x & 3;
  const int ot4 = (threadIdx.x & 15) << 2;
  const int xq4 = (threadIdx.x >> 4) << 2;
  for (int base0 = cb*32; base0 < M; base0 += (gridDim.x >> 1)*32){
    __syncthreads();
    {
      const float* xp = X + (size_t)(base0 + xid)*128 + part*32;
      float v[32];
      #pragma unroll
      for (int k=0;k<32;k+=4){
        float4 t = *(const float4*)(xp + k);
        v[k]=t.x; v[k+1]=t.y; v[k+2]=t.z; v[k+3]=t.w;
      }
      if (do_ln){
        float s=0.f, s2=0.f;
        #pragma unroll
        for (int k=0;k<32;k++){ s += v[k]; s2 = fmaf(v[k],v[k],s2); }
        s  += __shfl_xor(s, 2, 4);  s  += __shfl_xor(s, 1, 4);
        s2 += __shfl_xor(s2, 2, 4); s2 += __shfl_xor(s2, 1, 4);
        float mean = s * (1.f/128.f);
        float var  = fmaxf(s2*(1.f/128.f) - mean*mean, 0.f);
        float rstd = rsqrtf(var + 1e-5f);
        #pragma unroll
        for (int k=0;k<32;k++){
          int c = part*32 + k;
          v[k] = fmaf((v[k]-mean)*rstd, sg[c], sb[c]);
        }
      }
      #pragma unroll
      for (int k=0;k<32;k++) sln[(part*32+k)*32 + xid] = v[k];
    }
    __syncthreads();
    float acc[4][4];
    #pragma unroll
    for (int a=0;a<4;a++){ acc[a][0]=0.f;acc[a][1]=0.f;acc[a][2]=0.f;acc[a][3]=0.f; }
    #pragma unroll 2
    for (int c=0;c<128;c++){
      float4 w4 = *(const float4*)&sW[(c<<6) + ot4];
      float4 t4 = *(const float4*)&sln[(c<<5) + xq4];
      acc[0][0]=fmaf(w4.x,t4.x,acc[0][0]); acc[0][1]=fmaf(w4.x,t4.y,acc[0][1]);
      acc[0][2]=fmaf(w4.x,t4.z,acc[0][2]); acc[0][3]=fmaf(w4.x,t4.w,acc[0][3]);
      acc[1][0]=fmaf(w4.y,t4.x,acc[1][0]); acc[1][1]=fmaf(w4.y,t4.y,acc[1][1]);
      acc[1][2]=fmaf(w4.y,t4.z,acc[1][2]); acc[1][3]=fmaf(w4.y,t4.w,acc[1][3]);
      acc[2][0]=fmaf(w4.z,t4.x,acc[2][0]); acc[2][1]=fmaf(w4.z,t4.y,acc[2][1]);
      acc[2][2]=fmaf(w4.z,t4.z,acc[2][2]); acc[2][3]=fmaf(w4.z,t4.w,acc[2][3]);
      acc[3][0]=fmaf(w4.w,t4.x,acc[3][0]); acc[3][1]=fmaf(w4.w,t4.y,acc[3][1]);
      acc[3][2]=fmaf(w4.w,t4.z,acc[3][2]); acc[3][3]=fmaf(w4.w,t4.w,acc[3][3]);
    }
    int o_col = (colh<<6) + ot4;
    float4 b4 = *(const float4*)&sbias[ot4];
    #pragma unroll
    for (int xx=0; xx<4; xx++){
      int r = base0 + xq4 + xx;
      float o0 = acc[0][xx] + b4.x;
      float o1 = acc[1][xx] + b4.y;
      float o2 = acc[2][xx] + b4.z;
      float o3 = acc[3][xx] + b4.w;
      if (skip_mode == 1){
        // skip = x (B,128,64,64) at pixel derived from token-major row r
        int b = r >> 12, l = (r >> 6) & 63, pp = r & 63;
        int pix = (((l>>3)*8 + (pp>>3)) << 6) + (l&7)*8 + (pp&7);
        const float* sp = skipp + (size_t)b*524288 + (size_t)o_col*4096 + pix;
        o0 += sp[0]; o1 += sp[4096]; o2 += sp[8192]; o3 += sp[12288];
      } else if (skip_mode == 2){
        float4 sk = *(const float4*)&skipp[(size_t)r*128 + o_col];
        o0 += sk.x; o1 += sk.y; o2 += sk.z; o3 += sk.w;
      }
      size_t orow = (outmode == 0) ? (size_t)r : remap_kv(r, outmode);
      *(float4*)&OUT[orow*128 + o_col] = make_float4(o0,o1,o2,o3);
    }
  }
}

// attention core: one block per (b,l,head). stage1: 384 thr = 6 cameras x 64
// pixels (one token each), camera-mean folded in (before Wp: linear => exact).
// stage2: 256 thr = 4 key-quarters x 64 pixels (queries dedup'd over cameras).
// K/V staged through LDS in 3 tiles of 88 keys; unnormalized softmax (scores
// bounded << 88 so exp cannot overflow; identical math to max-sub softmax).
__global__ __launch_bounds__(384) void k_attn(const float* __restrict__ QP,
    const float* __restrict__ KP, const float* __restrict__ VP,
    float* __restrict__ AO, int nrep, int nQ){
  __shared__ float Ksh[88*32];
  __shared__ float Vsh[88*32];
  __shared__ float po[64*33];
  int blk = blockIdx.x;
  int hd = blk & 3; int bl = blk >> 2;       // bl = b*64 + l
  size_t kvbase = (size_t)bl*264*128 + hd*32;
  int p = threadIdx.x & 63;
  int g = threadIdx.x >> 6;
  int t, lo, hi;
  if (nrep == 6){ t = g*64 + p; lo = 0;    hi = 88; }
  else          { t = p;        lo = g*22; hi = lo + 22; }
  const float scale = 0.17677669529663687f;  // 32^-0.5
  float q[32];
  {
    const float* qp = QP + ((size_t)bl*nQ + t)*128 + hd*32;
    #pragma unroll
    for (int i=0;i<32;i+=4){
      float4 tq = *(const float4*)(qp + i);
      q[i]=tq.x*scale; q[i+1]=tq.y*scale; q[i+2]=tq.z*scale; q[i+3]=tq.w*scale;
    }
  }
  float oacc[32];
  #pragma unroll
  for (int i=0;i<32;i++) oacc[i]=0.f;
  float lsum = 0.f;
  for (int tile=0; tile<3; tile++){
    __syncthreads();
    for (int idx=threadIdx.x; idx<5632; idx+=blockDim.x){
      int row = idx >> 5, d = idx & 31;
      if (row < 88) Ksh[idx] = KP[kvbase + (size_t)(tile*88 + row)*128 + d];
      else          Vsh[(row-88)*32 + d] = VP[kvbase + (size_t)(tile*88 + row - 88)*128 + d];
    }
    __syncthreads();
    for (int u=lo; u<hi; u++){
      const float* kr = Ksh + u*32;
      float s0=0.f,s1=0.f,s2=0.f,s3=0.f;
      #pragma unroll
      for (int i=0;i<32;i+=4){
        float4 kk = *(const float4*)(kr + i);
        s0 = fmaf(q[i],   kk.x, s0);
        s1 = fmaf(q[i+1], kk.y, s1);
        s2 = fmaf(q[i+2], kk.z, s2);
        s3 = fmaf(q[i+3], kk.w, s3);
      }
      float e = __expf((s0+s1)+(s2+s3));
      lsum += e;
      const float* vr = Vsh + u*32;
      #pragma unroll
      for (int i=0;i<32;i+=4){
        float4 vv = *(const float4*)(vr + i);
        oacc[i]   = fmaf(e, vv.x, oacc[i]);
        oacc[i+1] = fmaf(e, vv.y, oacc[i+1]);
        oacc[i+2] = fmaf(e, vv.z, oacc[i+2]);
        oacc[i+3] = fmaf(e, vv.w, oacc[i+3]);
      }
    }
  }
  if (nrep == 6){
    float inv = 1.f/lsum;
    #pragma unroll
    for (int i=0;i<32;i++) oacc[i] *= inv;
    // accumulate cameras: (3->0),(4->1),(5->2),(1->0),(2->0) via one LDS slab
    const int srcs[5] = {3,4,5,1,2};
    const int dsts[5] = {0,1,2,0,0};
    #pragma unroll
    for (int rr=0; rr<5; rr++){
      __syncthreads();
      if (g == srcs[rr]){
        float* d = po + p*33;
        #pragma unroll
        for (int i=0;i<32;i++) d[i] = oacc[i];
      }
      __syncthreads();
      if (g == dsts[rr]){
        const float* d = po + p*33;
        #pragma unroll
        for (int i=0;i<32;i++) oacc[i] += d[i];
      }
    }
    if (g == 0){
      float* dst = AO + ((size_t)bl*64 + p)*128 + hd*32;
      #pragma unroll
      for (int i=0;i<32;i+=4)
        *(float4*)(dst+i) = make_float4(oacc[i]*(1.f/6.f), oacc[i+1]*(1.f/6.f),
                                        oacc[i+2]*(1.f/6.f), oacc[i+3]*(1.f/6.f));
    }
  } else {
    #pragma unroll
    for (int rr=1; rr<4; rr++){
      __syncthreads();
      if (g == rr){
        float* d = po + p*33;
        #pragma unroll
        for (int i=0;i<32;i++) d[i] = oacc[i];
        d[32] = lsum;
      }
      __syncthreads();
      if (g == 0){
        const float* d = po + p*33;
        #pragma unroll
        for (int i=0;i<32;i++) oacc[i] += d[i];
        lsum += d[32];
      }
    }
    if (g == 0){
      float inv = 1.f/lsum;
      float* dst = AO + ((size_t)bl*64 + p)*128 + hd*32;
      #pragma unroll
      for (int i=0;i<32;i+=4)
        *(float4*)(dst+i) = make_float4(oacc[i]*inv, oacc[i+1]*inv,
                                        oacc[i+2]*inv, oacc[i+3]*inv);
    }
  }
}

// y = x + gelu(LN(x)@Wa + ba)@Wb + bb   (exact gelu via erf)
__global__ __launch_bounds__(128) void k_mlp(const float* __restrict__ X,
    const float* __restrict__ pg, const float* __restrict__ pb,
    const float* __restrict__ Wa, const float* __restrict__ ba,
    const float* __restrict__ Wb, const float* __restrict__ bb2,
    float* __restrict__ OUT, int M){
  __shared__ float sraw[8*128];
  __shared__ float sln[128*8];
  __shared__ float sh[256*8];
  int xid = threadIdx.x >> 4, part = threadIdx.x & 15;
  for (int base0 = blockIdx.x*8; base0 < M; base0 += gridDim.x*8){
    __syncthreads();
    {
      const float* xp = X + (size_t)(base0 + xid)*128 + part*8;
      float v[8];
      #pragma unroll
      for (int k=0;k<8;k+=4){
        float4 t = *(const float4*)(xp + k);
        v[k]=t.x; v[k+1]=t.y; v[k+2]=t.z; v[k+3]=t.w;
      }
      float s=0.f, s2=0.f;
      #pragma unroll
      for (int k=0;k<8;k++){ s += v[k]; s2 = fmaf(v[k],v[k],s2); }
      #pragma unroll
      for (int off=8; off>0; off>>=1){ s += __shfl_xor(s, off, 16); s2 += __shfl_xor(s2, off, 16); }
      float mean = s*(1.f/128.f);
      float rstd = rsqrtf(fmaxf(s2*(1.f/128.f) - mean*mean, 0.f) + 1e-5f);
      #pragma unroll
      for (int k=0;k<8;k++){
        int c = part*8 + k;
        sraw[xid*128 + c] = v[k];
        sln[c*8 + xid] = fmaf((v[k]-mean)*rstd, pg[c], pb[c]);
      }
    }
    __syncthreads();
    {
      float a0[8]={0,0,0,0,0,0,0,0}, a1[8]={0,0,0,0,0,0,0,0};
      const float* wap = Wa + threadIdx.x*2;
      #pragma unroll 2
      for (int c=0;c<128;c++){
        float2 w = *(const float2*)(wap + c*256);
        float4 t0 = *(const float4*)&sln[c*8];
        float4 t1 = *(const float4*)&sln[c*8+4];
        a0[0]=fmaf(w.x,t0.x,a0[0]); a0[1]=fmaf(w.x,t0.y,a0[1]);
        a0[2]=fmaf(w.x,t0.z,a0[2]); a0[3]=fmaf(w.x,t0.w,a0[3]);
        a0[4]=fmaf(w.x,t1.x,a0[4]); a0[5]=fmaf(w.x,t1.y,a0[5]);
        a0[6]=fmaf(w.x,t1.z,a0[6]); a0[7]=fmaf(w.x,t1.w,a0[7]);
        a1[0]=fmaf(w.y,t0.x,a1[0]); a1[1]=fmaf(w.y,t0.y,a1[1]);
        a1[2]=fmaf(w.y,t0.z,a1[2]); a1[3]=fmaf(w.y,t0.w,a1[3]);
        a1[4]=fmaf(w.y,t1.x,a1[4]); a1[5]=fmaf(w.y,t1.y,a1[5]);
        a1[6]=fmaf(w.y,t1.z,a1[6]); a1[7]=fmaf(w.y,t1.w,a1[7]);
      }
      float b0 = ba[threadIdx.x*2], b1 = ba[threadIdx.x*2+1];
      #pragma unroll
      for (int x=0;x<8;x++){
        float h0 = a0[x] + b0;
        float h1 = a1[x] + b1;
        sh[(threadIdx.x*2)*8 + x]   = 0.5f*h0*(1.f + erff(h0*0.70710678118654752f));
        sh[(threadIdx.x*2+1)*8 + x] = 0.5f*h1*(1.f + erff(h1*0.70710678118654752f));
      }
    }
    __syncthreads();
    {
      float acc[8]={0,0,0,0,0,0,0,0};
      const float* wbp = Wb + threadIdx.x;
      #pragma unroll 2
      for (int j=0;j<256;j++){
        float w = wbp[j*128];
        float4 h0 = *(const float4*)&sh[j*8];
        float4 h1 = *(const float4*)&sh[j*8+4];
        acc[0]=fmaf(w,h0.x,acc[0]); acc[1]=fmaf(w,h0.y,acc[1]);
        acc[2]=fmaf(w,h0.z,acc[2]); acc[3]=fmaf(w,h0.w,acc[3]);
        acc[4]=fmaf(w,h1.x,acc[4]); acc[5]=fmaf(w,h1.y,acc[5]);
        acc[6]=fmaf(w,h1.z,acc[6]); acc[7]=fmaf(w,h1.w,acc[7]);
      }
      float bo = bb2[threadIdx.x];
      #pragma unroll
      for (int x=0;x<8;x++)
        OUT[(size_t)(base0+x)*128 + threadIdx.x] = acc[x] + bo + sraw[x*128 + threadIdx.x];
    }
  }
}

// final LN + transpose to (B,128,64,64)
__global__ __launch_bounds__(128) void k_final(const float* __restrict__ X,
    const float* __restrict__ g, const float* __restrict__ be,
    float* __restrict__ out){
  __shared__ float st[1024];
  __shared__ float sm[8], sr[8];
  int r0 = blockIdx.x*8;
  int b = r0 >> 12, l = (r0 >> 6) & 63, p0 = r0 & 63;
  int h = (l >> 3)*8 + (p0 >> 3);
  int wbase = (l & 7)*8;
  for (int idx=threadIdx.x; idx<1024; idx+=128) st[idx] = X[(size_t)r0*128 + idx];
  __syncthreads();
  int xid = threadIdx.x >> 4, part = threadIdx.x & 15;
  float s=0.f, s2=0.f;
  #pragma unroll
  for (int k=0;k<8;k++){
    float v = st[xid*128 + part*8 + k];
    s += v; s2 = fmaf(v,v,s2);
  }
  #pragma unroll
  for (int off=8; off>0; off>>=1){ s += __shfl_xor(s, off, 16); s2 += __shfl_xor(s2, off, 16); }
  if (part == 0){
    float mean = s*(1.f/128.f);
    sm[xid] = mean;
    sr[xid] = rsqrtf(fmaxf(s2*(1.f/128.f) - mean*mean, 0.f) + 1e-5f);
  }
  __syncthreads();
  int o = threadIdx.x;
  float go = g[o], bo = be[o];
  size_t obase = ((size_t)(b*128 + o))*4096 + h*64 + wbase;
  float res[8];
  #pragma unroll
  for (int x=0;x<8;x++) res[x] = fmaf((st[x*128+o]-sm[x])*sr[x], go, bo);
  *(float4*)&out[obase]   = make_float4(res[0],res[1],res[2],res[3]);
  *(float4*)&out[obase+4] = make_float4(res[4],res[5],res[6],res[7]);
}

extern "C" void kernel_launch(void* const* d_in, const int* in_sizes, int n_in,
                              void* d_out, int out_size, void* d_ws, size_t ws_size,
                              hipStream_t stream) {
  (void)in_sizes; (void)n_in; (void)out_size; (void)ws_size;
  const float* x     = (const float*)d_in[1];
  const float* gridp = (const float*)d_in[2];
  const float* feat  = (const float*)d_in[3];
  const float* Iinv  = (const float*)d_in[4];
  const float* Einv  = (const float*)d_in[5];
  const float* gfl   = (const float*)d_in[6];
  const float* bfl   = (const float*)d_in[7];
  const float* Wfl   = (const float*)d_in[8];
  const float* gfp   = (const float*)d_in[9];
  const float* bfp   = (const float*)d_in[10];
  const float* Wfp   = (const float*)d_in[11];
  const float* Wbev  = (const float*)d_in[12];
  const float* bbev  = (const float*)d_in[13];
  const float* Wimg  = (const float*)d_in[14];
  const float* Wcam  = (const float*)d_in[15];
  const float* alng  = (const float*)d_in[16];
  const float* alnb  = (const float*)d_in[17];
  const float* aWqkv = (const float*)d_in[18];
  const float* abqkv = (const float*)d_in[19];
  const float* aWp   = (const float*)d_in[20];
  const float* abp   = (const float*)d_in[21];
  const float* png   = (const float*)d_in[22];
  const float* pnb   = (const float*)d_in[23];
  const float* Wma   = (const float*)d_in[24];
  const float* bma   = (const float*)d_in[25];
  const float* Wmb   = (const float*)d_in[26];
  const float* bmb   = (const float*)d_in[27];
  const float* postg = (const float*)d_in[28];
  const float* postb = (const float*)d_in[29];
  float* out = (float*)d_out;
  float* ws  = (float*)d_ws;

  // workspace layout (floats); total 29,886,464 floats = 119.5 MB
  float* CE  = ws;                    // 1536 (pad 2048)
  float* K1  = ws + 2048;             // 4,325,376  (bn,p,c) key_im
  float* V1  = K1 + 4325376;          // 4,325,376  val_im
  float* KP  = V1 + 4325376;          // 4,325,376  (b,l,264,c)
  float* VP  = KP + 4325376;          // 4,325,376
  float* QP  = VP + 4325376;          // 6,291,456  (b,l,384|64,c)
  float* Qb  = QP + 6291456;          // 6,291,456  stage-1 raw q tokens
  float* AO  = Qb;                    // 1,048,576  (reuses Qb after QP built)
  float* CUR = Qb + 1048576;          // 1,048,576
  float* Q1  = Qb + 2097152;          // 1,048,576
  float* Q2  = Qb + 3145728;          // 1,048,576

  k_cembed<<<12, 128, 0, stream>>>(Einv, Wcam, CE);
  k_geom<<<4224, 128, 0, stream>>>(Iinv, Einv, Wimg, CE, K1);
  k_conv<<<4224, 128, 0, stream>>>(feat, gfl, bfl, Wfl, gfp, bfp, Wfp, K1, V1);
  k_bevq<<<6144, 128, 0, stream>>>(gridp, Wbev, bbev, CE, x, Qb);

  // ---- stage 1 ----
  k_lngemm<<<1024, 128, 0, stream>>>(Qb, alng+0,   alnb+0,   aWqkv+0,     abqkv+0,   QP, 49152, 0, 1, 0, nullptr);
  k_lngemm<<<1024, 128, 0, stream>>>(K1, alng+128, alnb+128, aWqkv+16384, abqkv+128, KP, 33792, 1, 1, 0, nullptr);
  k_lngemm<<<1024, 128, 0, stream>>>(V1, alng+256, alnb+256, aWqkv+32768, abqkv+256, VP, 33792, 1, 1, 0, nullptr);
  k_attn<<<512, 384, 0, stream>>>(QP, KP, VP, AO, 6, 384);
  k_lngemm<<<1024, 128, 0, stream>>>(AO, nullptr, nullptr, aWp+0, abp+0, CUR, 8192, 0, 0, 1, x);
  k_mlp<<<1024, 128, 0, stream>>>(CUR, png+0, pnb+0, Wma+0, bma+0, Wmb+0, bmb+0, Q1, 8192);

  // ---- stage 2 ----
  k_lngemm<<<1024, 128, 0, stream>>>(Q1, alng+384, alnb+384, aWqkv+49152, abqkv+384, QP, 8192, 0, 1, 0, nullptr);
  k_lngemm<<<1024, 128, 0, stream>>>(K1, alng+512, alnb+512, aWqkv+65536, abqkv+512, KP, 33792, 2, 1, 0, nullptr);
  k_lngemm<<<1024, 128, 0, stream>>>(V1, alng+640, alnb+640, aWqkv+81920, abqkv+640, VP, 33792, 2, 1, 0, nullptr);
  k_attn<<<512, 256, 0, stream>>>(QP, KP, VP, AO, 1, 64);
  k_lngemm<<<1024, 128, 0, stream>>>(AO, nullptr, nullptr, aWp+16384, abp+128, CUR, 8192, 0, 0, 2, Q1);
  k_mlp<<<1024, 128, 0, stream>>>(CUR, png+128, pnb+128, Wma+32768, bma+256, Wmb+32768, bmb+128, Q2, 8192);

  k_final<<<1024, 128, 0, stream>>>(Q2, postg, postb, out);
}

// Round 2
// 665.942 us; speedup vs baseline: 1.3038x; 1.3038x over previous
//
#include <hip/hip_runtime.h>
#include <math.h>

// CrossViewSwapAttention forward. Round 2: GEMM family on bf16 MFMA
// (mfma_f32_16x16x32_bf16), attention still fp32 VALU (next round).
// B=2 N=6 H=W=64 FH=32 FW=88 DIM=128 HEADS=4 DH=32 QW=8x8 KW=4x11

typedef __attribute__((ext_vector_type(8))) short short8;
typedef __attribute__((ext_vector_type(4))) float f32x4;

#define LDA 136   // K(=128) + 8 shorts pitch: 272B rows -> 2-way-free b128 frag reads

__device__ __forceinline__ unsigned short f2bf(float f){
  union { float f; unsigned u; } v; v.f = f;
  unsigned r = v.u + 0x7FFF + ((v.u >> 16) & 1);   // RNE
  return (unsigned short)(r >> 16);
}

__device__ __forceinline__ void store_bf16x8(unsigned short* p, const float* v){
  union { short8 s8; unsigned short u[8]; } u;
  #pragma unroll
  for (int i=0;i<8;i++) u.u[i] = f2bf(v[i]);
  *(short8*)p = u.s8;
}

__device__ __forceinline__ size_t remap_kv(int tok, int mode){
  // tok = bn*2816 + i*88 + j  ->  KP/VP row ((b*64+l)*264 + t)
  int bn = tok / 2816; int p = tok - bn*2816;
  int b = bn / 6, n = bn - b*6;
  int i = p / 88, j = p - i*88;
  int l, t;
  if (mode == 1){            // stage 1: _win(k, 4, 11)
    int jw = j / 11;
    l = (i >> 2)*8 + jw;
    t = n*44 + (i & 3)*11 + (j - jw*11);
  } else {                   // stage 2: _gridwin(k, 4, 11)
    l = (i & 7)*8 + (j & 7);
    t = n*44 + (i >> 3)*11 + (j >> 3);
  }
  return (size_t)((b*64 + l)*264 + t);
}

// c_embed[bn][o] = sum_c W_cam[o][c] * E_inv[bn][c][3]
__global__ __launch_bounds__(128) void k_cembed(const float* __restrict__ Einv,
                                                const float* __restrict__ Wcam,
                                                float* __restrict__ CE){
  int bn = blockIdx.x, o = threadIdx.x;
  const float* E = Einv + bn*16;
  const float* W = Wcam + o*4;
  CE[bn*128 + o] = W[0]*E[3] + W[1]*E[7] + W[2]*E[11] + W[3]*E[15];
}

// one-time weight prep: fp32 [k][n] -> bf16 [n][k] (or straight copy for
// W_fl/W_fp which are already [o][c]=[n][k]).
__global__ __launch_bounds__(256) void k_wprep(const float* __restrict__ qkv,
    const float* __restrict__ wp, const float* __restrict__ wma,
    const float* __restrict__ wmb, const float* __restrict__ wfl,
    const float* __restrict__ wfp, unsigned short* __restrict__ Wt){
  const int sel[14]  = {0,0,0,0,0,0,1,1,2,2,3,3,4,5};
  const int soff[14] = {0,16384,32768,49152,65536,81920,0,16384,0,32768,0,32768,0,0};
  const int doff[14] = {0,16384,32768,49152,65536,81920,98304,114688,131072,163840,196608,229376,262144,278528};
  const int Ks[14]   = {128,128,128,128,128,128,128,128,128,128,256,256,128,128};
  const int Ns[14]   = {128,128,128,128,128,128,128,128,256,256,128,128,128,128};
  const int trs[14]  = {1,1,1,1,1,1,1,1,1,1,1,1,0,0};
  int sg = blockIdx.x >> 2, q = blockIdx.x & 3;
  const float* srcs[6] = {qkv, wp, wma, wmb, wfl, wfp};
  const float* src = srcs[sel[sg]] + soff[sg];
  unsigned short* dst = Wt + doff[sg];
  int K = Ks[sg], N = Ns[sg];
  int quarter = (K*N) >> 2;
  for (int idx = q*quarter + threadIdx.x; idx < (q+1)*quarter; idx += 256){
    int n = idx / K, k = idx - n*K;
    float v = trs[sg] ? src[k*N + n] : src[idx];
    dst[idx] = f2bf(v);
  }
}

// img_embed (normalized over channel) -> K1 (channel-last, (bn,p,c))
__global__ __launch_bounds__(128) void k_geom(const float* __restrict__ Iinv,
                                              const float* __restrict__ Einv,
                                              const float* __restrict__ Wimg,
                                              const float* __restrict__ CE,
                                              float* __restrict__ K1){
  int tile = blockIdx.x;               // bn*352 + tp  (8 pixels per block)
  int bn = tile / 352; int p0 = (tile - bn*352)*8;
  int xid = threadIdx.x >> 4, part = threadIdx.x & 15;
  int p = p0 + xid;
  int i = p / 88, j = p - i*88;
  float xs = (float)j * (480.0f/87.0f);
  float ys = (float)i * (224.0f/31.0f);
  const float* I = Iinv + bn*9;
  const float* E = Einv + bn*16;
  float c0 = I[0]*xs + I[1]*ys + I[2];
  float c1 = I[3]*xs + I[4]*ys + I[5];
  float c2 = I[6]*xs + I[7]*ys + I[8];
  float d0 = E[0]*c0 + E[1]*c1 + E[2]*c2 + E[3];
  float d1 = E[4]*c0 + E[5]*c1 + E[6]*c2 + E[7];
  float d2 = E[8]*c0 + E[9]*c1 + E[10]*c2 + E[11];
  float d3 = E[12]*c0 + E[13]*c1 + E[14]*c2 + E[15];
  float v[8]; float sq = 0.f;
  #pragma unroll
  for (int k=0;k<8;k++){
    int o = part*8 + k;
    const float* W = Wimg + o*4;
    float de = W[0]*d0 + W[1]*d1 + W[2]*d2 + W[3]*d3;
    float vv = de - CE[bn*128 + o];
    v[k] = vv; sq = fmaf(vv, vv, sq);
  }
  #pragma unroll
  for (int off=8; off>0; off>>=1) sq += __shfl_xor(sq, off, 16);
  float rn = 1.0f / fmaxf(sqrtf(sq), 1e-12f);
  float* dst = K1 + (size_t)(bn*2816 + p)*128 + part*8;
  #pragma unroll
  for (int k=0;k<8;k++) dst[k] = v[k]*rn;
}

// query = normalize(w_embed - c_embed) + x, then stage-1 q LayerNorm folded in,
// emitted bf16 in stage-1 window-token order -> feeds MFMA q-gemm directly.
__global__ __launch_bounds__(128) void k_bevq2(const float* __restrict__ gridp,
    const float* __restrict__ Wbev, const float* __restrict__ bbev,
    const float* __restrict__ CE, const float* __restrict__ x,
    const float* __restrict__ lg, const float* __restrict__ lb,
    unsigned short* __restrict__ Qh){
  int tile = blockIdx.x;               // bn*512 + tp (8 pixels per block)
  int bn = tile >> 9; int pp0 = (tile & 511) << 3;
  int b = bn / 6, n = bn - b*6;
  int xid = threadIdx.x >> 4, part = threadIdx.x & 15;
  int pix = pp0 + xid;
  int h = pix >> 6, w = pix & 63;
  float g0 = gridp[pix], g1 = gridp[4096 + pix];
  float v[8]; float sq = 0.f;
  #pragma unroll
  for (int k=0;k<8;k++){
    int o = part*8 + k;
    float we = Wbev[o*2]*g0 + Wbev[o*2+1]*g1 + bbev[o];
    float vv = we - CE[bn*128 + o];
    v[k] = vv; sq = fmaf(vv, vv, sq);
  }
  #pragma unroll
  for (int off=8; off>0; off>>=1) sq += __shfl_xor(sq, off, 16);
  float rn = 1.0f / fmaxf(sqrtf(sq), 1e-12f);
  const float* xp = x + ((size_t)b*128)*4096 + pix;
  float q[8]; float s=0.f, s2=0.f;
  #pragma unroll
  for (int k=0;k<8;k++){
    int o = part*8 + k;
    q[k] = fmaf(v[k], rn, xp[(size_t)o*4096]);
    s += q[k]; s2 = fmaf(q[k], q[k], s2);
  }
  #pragma unroll
  for (int off=8; off>0; off>>=1){ s += __shfl_xor(s, off, 16); s2 += __shfl_xor(s2, off, 16); }
  float mean = s*(1.f/128.f);
  float rstd = rsqrtf(fmaxf(s2*(1.f/128.f) - mean*mean, 0.f) + 1e-5f);
  int l = (h>>3)*8 + (w>>3);
  int t = n*64 + (h&7)*8 + (w&7);
  size_t row = (size_t)((b*64 + l)*384 + t);
  float o8[8];
  #pragma unroll
  for (int k=0;k<8;k++){
    int c = part*8 + k;
    o8[k] = fmaf((q[k]-mean)*rstd, lg[c], lb[c]);
  }
  store_bf16x8(Qh + row*128 + part*8, o8);
}

// Universal MFMA GEMM: OUT[r][col] = act(A(X) @ Wt^T + bias) (+skip), K=128,N=128.
// pre: 0 = fp32 X rows (optional LN), 1 = conv (feat + BN + relu, transpose-load),
//      2 = pre-LN'd bf16 rows (Qh).
// A-frag: lane m=l&15, k=quad*8+j ; B-frag: n=l&15, k=quad*8+j ; D: n=l&15, m=quad*4+r.
__global__ __launch_bounds__(256) void k_gemm(
    const float* __restrict__ Xf, const unsigned short* __restrict__ Xh,
    int ldx, int xoff,
    const float* __restrict__ lg, const float* __restrict__ lb,
    const unsigned short* __restrict__ Wt, int ldw, int woff,
    const float* __restrict__ bias,
    float* __restrict__ OUT, int ldout, int ooff,
    int M, int pre, int do_ln, int act, int outmode, int skip_mode,
    const float* __restrict__ skipp){
  __shared__ unsigned short sA[64*LDA];
  __shared__ unsigned short sW[128*LDA];
  __shared__ float sg[128], sb[128], sbias[128];
  int tid = threadIdx.x;
  // stage W (bf16 [n][k]) into LDS with +8 pad
  for (int i = tid; i < 2048; i += 256){
    int n = i >> 4, k8 = (i & 15) << 3;
    short8 v = *(const short8*)(Wt + (size_t)n*ldw + woff + k8);
    *(short8*)&sW[n*LDA + k8] = v;
  }
  if (tid < 128){
    if (do_ln || pre == 1){ sg[tid] = lg[tid]; sb[tid] = lb[tid]; }
    sbias[tid] = bias ? bias[tid] : 0.f;
  }
  __syncthreads();
  const int lane = tid & 63, wv = tid >> 6;
  const int lane15 = lane & 15, quad = lane >> 4;
  const int n0 = wv * 32;
  const float bs0 = sbias[n0 + lane15], bs1 = sbias[n0 + lane15 + 16];
  const int col0 = n0 + lane15, col1 = col0 + 16;
  const int chunks = M >> 6;
  const float RSQ = rsqrtf(1.0f + 1e-5f);
  for (int ch = blockIdx.x; ch < chunks; ch += gridDim.x){
    int base = ch << 6;
    __syncthreads();     // previous compute done reading sA
    if (pre == 0){
      int r = tid >> 2, part = tid & 3;
      const float* xp = Xf + (size_t)(base + r)*ldx + xoff + part*32;
      float v[32];
      #pragma unroll
      for (int k=0;k<32;k+=4){
        float4 t4 = *(const float4*)(xp + k);
        v[k]=t4.x; v[k+1]=t4.y; v[k+2]=t4.z; v[k+3]=t4.w;
      }
      if (do_ln){
        float s=0.f, s2=0.f;
        #pragma unroll
        for (int k=0;k<32;k++){ s += v[k]; s2 = fmaf(v[k],v[k],s2); }
        s  += __shfl_xor(s, 2, 4);  s  += __shfl_xor(s, 1, 4);
        s2 += __shfl_xor(s2, 2, 4); s2 += __shfl_xor(s2, 1, 4);
        float mean = s * (1.f/128.f);
        float rstd = rsqrtf(fmaxf(s2*(1.f/128.f) - mean*mean, 0.f) + 1e-5f);
        #pragma unroll
        for (int k=0;k<32;k++){
          int c = part*32 + k;
          v[k] = fmaf((v[k]-mean)*rstd, sg[c], sb[c]);
        }
      }
      unsigned short* ap = sA + r*LDA + part*32;
      store_bf16x8(ap, v); store_bf16x8(ap+8, v+8);
      store_bf16x8(ap+16, v+16); store_bf16x8(ap+24, v+24);
    } else if (pre == 2){
      int r = tid >> 2, part = tid & 3;
      const short8* src = (const short8*)(Xh + (size_t)(base + r)*128 + part*32);
      short8* dst = (short8*)(sA + r*LDA + part*32);
      dst[0]=src[0]; dst[1]=src[1]; dst[2]=src[2]; dst[3]=src[3];
    } else {  // pre == 1: conv A from feat (bn,c,p), BN eval + relu
      int prow = tid & 63, cseg = tid >> 6;
      int bn = base / 2816;                 // chunks never straddle bn (2816%64==0)
      int p = base - bn*2816 + prow;
      const float* fb = Xf + ((size_t)bn*128 + cseg*32)*2816 + p;
      #pragma unroll
      for (int i=0;i<32;i+=2){
        int c = cseg*32 + i;
        float t0 = fb[(size_t)i*2816] * RSQ;
        float t1 = fb[(size_t)(i+1)*2816] * RSQ;
        float y0 = fmaxf(fmaf(t0, sg[c],   sb[c]),   0.f);
        float y1 = fmaxf(fmaf(t1, sg[c+1], sb[c+1]), 0.f);
        unsigned u = (unsigned)f2bf(y0) | ((unsigned)f2bf(y1) << 16);
        *(unsigned*)&sA[prow*LDA + c] = u;
      }
    }
    __syncthreads();
    f32x4 acc[4][2];
    #pragma unroll
    for (int mt=0; mt<4; mt++){ acc[mt][0] = (f32x4)0.f; acc[mt][1] = (f32x4)0.f; }
    const unsigned short* aptr = sA + lane15*LDA + quad*8;
    const unsigned short* bptr = sW + (n0 + lane15)*LDA + quad*8;
    #pragma unroll
    for (int kk=0; kk<4; kk++){
      short8 a0 = *(const short8*)(aptr + kk*32);
      short8 a1 = *(const short8*)(aptr + 16*LDA + kk*32);
      short8 a2 = *(const short8*)(aptr + 32*LDA + kk*32);
      short8 a3 = *(const short8*)(aptr + 48*LDA + kk*32);
      short8 b0 = *(const short8*)(bptr + kk*32);
      short8 b1 = *(const short8*)(bptr + 16*LDA + kk*32);
      acc[0][0] = __builtin_amdgcn_mfma_f32_16x16x32_bf16(a0,b0,acc[0][0],0,0,0);
      acc[1][0] = __builtin_amdgcn_mfma_f32_16x16x32_bf16(a1,b0,acc[1][0],0,0,0);
      acc[2][0] = __builtin_amdgcn_mfma_f32_16x16x32_bf16(a2,b0,acc[2][0],0,0,0);
      acc[3][0] = __builtin_amdgcn_mfma_f32_16x16x32_bf16(a3,b0,acc[3][0],0,0,0);
      acc[0][1] = __builtin_amdgcn_mfma_f32_16x16x32_bf16(a0,b1,acc[0][1],0,0,0);
      acc[1][1] = __builtin_amdgcn_mfma_f32_16x16x32_bf16(a1,b1,acc[1][1],0,0,0);
      acc[2][1] = __builtin_amdgcn_mfma_f32_16x16x32_bf16(a2,b1,acc[2][1],0,0,0);
      acc[3][1] = __builtin_amdgcn_mfma_f32_16x16x32_bf16(a3,b1,acc[3][1],0,0,0);
    }
    #pragma unroll
    for (int mt=0; mt<4; mt++){
      #pragma unroll
      for (int nt=0; nt<2; nt++){
        int col = nt ? col1 : col0;
        float bsv = nt ? bs1 : bs0;
        #pragma unroll
        for (int r4=0; r4<4; r4++){
          int rrow = base + mt*16 + quad*4 + r4;
          float v = acc[mt][nt][r4] + bsv;
          if (act == 1) v = 0.5f*v*(1.f + erff(v*0.70710678118654752f));
          if (skip_mode == 1){
            int bb = rrow >> 12, l = (rrow >> 6) & 63, pp = rrow & 63;
            int pix = (((l>>3)*8 + (pp>>3)) << 6) + (l&7)*8 + (pp&7);
            v += skipp[(size_t)bb*524288 + (size_t)col*4096 + pix];
          } else if (skip_mode == 2){
            v += skipp[(size_t)rrow*128 + col];
          }
          size_t orow = outmode ? remap_kv(rrow, outmode) : (size_t)rrow;
          OUT[orow*(size_t)ldout + ooff + col] = v;
        }
      }
    }
  }
}

// attention core (unchanged from round 1): one block per (b,l,head).
__global__ __launch_bounds__(384) void k_attn(const float* __restrict__ QP,
    const float* __restrict__ KP, const float* __restrict__ VP,
    float* __restrict__ AO, int nrep, int nQ){
  __shared__ float Ksh[88*32];
  __shared__ float Vsh[88*32];
  __shared__ float po[64*33];
  int blk = blockIdx.x;
  int hd = blk & 3; int bl = blk >> 2;
  size_t kvbase = (size_t)bl*264*128 + hd*32;
  int p = threadIdx.x & 63;
  int g = threadIdx.x >> 6;
  int t, lo, hi;
  if (nrep == 6){ t = g*64 + p; lo = 0;    hi = 88; }
  else          { t = p;        lo = g*22; hi = lo + 22; }
  const float scale = 0.17677669529663687f;
  float q[32];
  {
    const float* qp = QP + ((size_t)bl*nQ + t)*128 + hd*32;
    #pragma unroll
    for (int i=0;i<32;i+=4){
      float4 tq = *(const float4*)(qp + i);
      q[i]=tq.x*scale; q[i+1]=tq.y*scale; q[i+2]=tq.z*scale; q[i+3]=tq.w*scale;
    }
  }
  float oacc[32];
  #pragma unroll
  for (int i=0;i<32;i++) oacc[i]=0.f;
  float lsum = 0.f;
  for (int tile=0; tile<3; tile++){
    __syncthreads();
    for (int idx=threadIdx.x; idx<5632; idx+=blockDim.x){
      int row = idx >> 5, d = idx & 31;
      if (row < 88) Ksh[idx] = KP[kvbase + (size_t)(tile*88 + row)*128 + d];
      else          Vsh[(row-88)*32 + d] = VP[kvbase + (size_t)(tile*88 + row - 88)*128 + d];
    }
    __syncthreads();
    for (int u=lo; u<hi; u++){
      const float* kr = Ksh + u*32;
      float s0=0.f,s1=0.f,s2=0.f,s3=0.f;
      #pragma unroll
      for (int i=0;i<32;i+=4){
        float4 kk = *(const float4*)(kr + i);
        s0 = fmaf(q[i],   kk.x, s0);
        s1 = fmaf(q[i+1], kk.y, s1);
        s2 = fmaf(q[i+2], kk.z, s2);
        s3 = fmaf(q[i+3], kk.w, s3);
      }
      float e = __expf((s0+s1)+(s2+s3));
      lsum += e;
      const float* vr = Vsh + u*32;
      #pragma unroll
      for (int i=0;i<32;i+=4){
        float4 vv = *(const float4*)(vr + i);
        oacc[i]   = fmaf(e, vv.x, oacc[i]);
        oacc[i+1] = fmaf(e, vv.y, oacc[i+1]);
        oacc[i+2] = fmaf(e, vv.z, oacc[i+2]);
        oacc[i+3] = fmaf(e, vv.w, oacc[i+3]);
      }
    }
  }
  if (nrep == 6){
    float inv = 1.f/lsum;
    #pragma unroll
    for (int i=0;i<32;i++) oacc[i] *= inv;
    const int srcs[5] = {3,4,5,1,2};
    const int dsts[5] = {0,1,2,0,0};
    #pragma unroll
    for (int rr=0; rr<5; rr++){
      __syncthreads();
      if (g == srcs[rr]){
        float* d = po + p*33;
        #pragma unroll
        for (int i=0;i<32;i++) d[i] = oacc[i];
      }
      __syncthreads();
      if (g == dsts[rr]){
        const float* d = po + p*33;
        #pragma unroll
        for (int i=0;i<32;i++) oacc[i] += d[i];
      }
    }
    if (g == 0){
      float* dst = AO + ((size_t)bl*64 + p)*128 + hd*32;
      #pragma unroll
      for (int i=0;i<32;i+=4)
        *(float4*)(dst+i) = make_float4(oacc[i]*(1.f/6.f), oacc[i+1]*(1.f/6.f),
                                        oacc[i+2]*(1.f/6.f), oacc[i+3]*(1.f/6.f));
    }
  } else {
    #pragma unroll
    for (int rr=1; rr<4; rr++){
      __syncthreads();
      if (g == rr){
        float* d = po + p*33;
        #pragma unroll
        for (int i=0;i<32;i++) d[i] = oacc[i];
        d[32] = lsum;
      }
      __syncthreads();
      if (g == 0){
        const float* d = po + p*33;
        #pragma unroll
        for (int i=0;i<32;i++) oacc[i] += d[i];
        lsum += d[32];
      }
    }
    if (g == 0){
      float inv = 1.f/lsum;
      float* dst = AO + ((size_t)bl*64 + p)*128 + hd*32;
      #pragma unroll
      for (int i=0;i<32;i+=4)
        *(float4*)(dst+i) = make_float4(oacc[i]*inv, oacc[i+1]*inv,
                                        oacc[i+2]*inv, oacc[i+3]*inv);
    }
  }
}

// final LN + transpose to (B,128,64,64)
__global__ __launch_bounds__(128) void k_final(const float* __restrict__ X,
    const float* __restrict__ g, const float* __restrict__ be,
    float* __restrict__ out){
  __shared__ float st[1024];
  __shared__ float sm[8], sr[8];
  int r0 = blockIdx.x*8;
  int b = r0 >> 12, l = (r0 >> 6) & 63, p0 = r0 & 63;
  int h = (l >> 3)*8 + (p0 >> 3);
  int wbase = (l & 7)*8;
  for (int idx=threadIdx.x; idx<1024; idx+=128) st[idx] = X[(size_t)r0*128 + idx];
  __syncthreads();
  int xid = threadIdx.x >> 4, part = threadIdx.x & 15;
  float s=0.f, s2=0.f;
  #pragma unroll
  for (int k=0;k<8;k++){
    float v = st[xid*128 + part*8 + k];
    s += v; s2 = fmaf(v,v,s2);
  }
  #pragma unroll
  for (int off=8; off>0; off>>=1){ s += __shfl_xor(s, off, 16); s2 += __shfl_xor(s2, off, 16); }
  if (part == 0){
    float mean = s*(1.f/128.f);
    sm[xid] = mean;
    sr[xid] = rsqrtf(fmaxf(s2*(1.f/128.f) - mean*mean, 0.f) + 1e-5f);
  }
  __syncthreads();
  int o = threadIdx.x;
  float go = g[o], bo = be[o];
  size_t obase = ((size_t)(b*128 + o))*4096 + h*64 + wbase;
  float res[8];
  #pragma unroll
  for (int x=0;x<8;x++) res[x] = fmaf((st[x*128+o]-sm[x])*sr[x], go, bo);
  *(float4*)&out[obase]   = make_float4(res[0],res[1],res[2],res[3]);
  *(float4*)&out[obase+4] = make_float4(res[4],res[5],res[6],res[7]);
}

extern "C" void kernel_launch(void* const* d_in, const int* in_sizes, int n_in,
                              void* d_out, int out_size, void* d_ws, size_t ws_size,
                              hipStream_t stream) {
  (void)in_sizes; (void)n_in; (void)out_size; (void)ws_size;
  const float* x     = (const float*)d_in[1];
  const float* gridp = (const float*)d_in[2];
  const float* feat  = (const float*)d_in[3];
  const float* Iinv  = (const float*)d_in[4];
  const float* Einv  = (const float*)d_in[5];
  const float* gfl   = (const float*)d_in[6];
  const float* bfl   = (const float*)d_in[7];
  const float* Wfl   = (const float*)d_in[8];
  const float* gfp   = (const float*)d_in[9];
  const float* bfp   = (const float*)d_in[10];
  const float* Wfp   = (const float*)d_in[11];
  const float* Wbev  = (const float*)d_in[12];
  const float* bbev  = (const float*)d_in[13];
  const float* Wimg  = (const float*)d_in[14];
  const float* Wcam  = (const float*)d_in[15];
  const float* alng  = (const float*)d_in[16];
  const float* alnb  = (const float*)d_in[17];
  const float* aWqkv = (const float*)d_in[18];
  const float* abqkv = (const float*)d_in[19];
  const float* aWp   = (const float*)d_in[20];
  const float* abp   = (const float*)d_in[21];
  const float* png   = (const float*)d_in[22];
  const float* pnb   = (const float*)d_in[23];
  const float* Wma   = (const float*)d_in[24];
  const float* bma   = (const float*)d_in[25];
  const float* Wmb   = (const float*)d_in[26];
  const float* bmb   = (const float*)d_in[27];
  const float* postg = (const float*)d_in[28];
  const float* postb = (const float*)d_in[29];
  float* out = (float*)d_out;
  float* ws  = (float*)d_ws;

  // ws layout (floats), total 27,936,768 floats = 111.7 MB
  float* CE  = ws;                               // 2048
  unsigned short* Wt = (unsigned short*)(ws + 2048);  // 294912 ushorts = 147456 f
  float* K1f = ws + 149504;                      // 4,325,376
  float* V1f = K1f + 4325376;
  float* KPf = V1f + 4325376;  float* H = KPf;   // H (8192x256) overlays KP
  float* VPf = KPf + 4325376;
  float* QPf = VPf + 4325376;                    // 6,291,456
  float* R   = QPf + 6291456;                    // 4,194,304 region
  unsigned short* Qbh = (unsigned short*)R;      // bf16 pre-LN q (dead after q-gemm)
  float* AO  = R;
  float* CUR = R + 1048576;
  float* Q1f = R + 2097152;
  float* Q2f = R + 3145728;

  // Wt sub-offsets (ushorts)
  unsigned short* WtQ1 = Wt;            unsigned short* WtK1 = Wt + 16384;
  unsigned short* WtV1 = Wt + 32768;    unsigned short* WtQ2 = Wt + 49152;
  unsigned short* WtK2 = Wt + 65536;    unsigned short* WtV2 = Wt + 81920;
  unsigned short* WtP1 = Wt + 98304;    unsigned short* WtP2 = Wt + 114688;
  unsigned short* WtMA1 = Wt + 131072;  unsigned short* WtMA2 = Wt + 163840;
  unsigned short* WtMB1 = Wt + 196608;  unsigned short* WtMB2 = Wt + 229376;
  unsigned short* WtFL = Wt + 262144;   unsigned short* WtFP = Wt + 278528;

  k_cembed<<<12, 128, 0, stream>>>(Einv, Wcam, CE);
  k_wprep<<<56, 256, 0, stream>>>(aWqkv, aWp, Wma, Wmb, Wfl, Wfp, Wt);
  k_geom<<<4224, 128, 0, stream>>>(Iinv, Einv, Wimg, CE, K1f);
  k_bevq2<<<6144, 128, 0, stream>>>(gridp, Wbev, bbev, CE, x, alng, alnb, Qbh);

  // conv: K1 += Wfp@relu(bn(feat)), V1 = Wfl@relu(bn(feat))
  k_gemm<<<512, 256, 0, stream>>>(feat, 0, 0,0, gfp, bfp, WtFP,128,0, nullptr,
                                  K1f,128,0, 33792, 1,0,0, 0, 2, K1f);
  k_gemm<<<512, 256, 0, stream>>>(feat, 0, 0,0, gfl, bfl, WtFL,128,0, nullptr,
                                  V1f,128,0, 33792, 1,0,0, 0, 0, nullptr);

  // ---- stage 1 ----
  k_gemm<<<512, 256, 0, stream>>>(nullptr, Qbh, 128,0, 0,0, WtQ1,128,0, abqkv,
                                  QPf,128,0, 49152, 2,0,0, 0, 0, nullptr);
  k_gemm<<<512, 256, 0, stream>>>(K1f, 0, 128,0, alng+128, alnb+128, WtK1,128,0, abqkv+128,
                                  KPf,128,0, 33792, 0,1,0, 1, 0, nullptr);
  k_gemm<<<512, 256, 0, stream>>>(V1f, 0, 128,0, alng+256, alnb+256, WtV1,128,0, abqkv+256,
                                  VPf,128,0, 33792, 0,1,0, 1, 0, nullptr);
  k_attn<<<512, 384, 0, stream>>>(QPf, KPf, VPf, AO, 6, 384);
  k_gemm<<<128, 256, 0, stream>>>(AO, 0, 128,0, 0,0, WtP1,128,0, abp,
                                  CUR,128,0, 8192, 0,0,0, 0, 1, x);
  k_gemm<<<128, 256, 0, stream>>>(CUR, 0, 128,0, png, pnb, WtMA1,128,0, bma,
                                  H,256,0,   8192, 0,1,1, 0, 0, nullptr);
  k_gemm<<<128, 256, 0, stream>>>(CUR, 0, 128,0, png, pnb, WtMA1+16384,128,0, bma+128,
                                  H,256,128, 8192, 0,1,1, 0, 0, nullptr);
  k_gemm<<<128, 256, 0, stream>>>(H, 0, 256,0, 0,0, WtMB1,256,0, bmb,
                                  Q1f,128,0, 8192, 0,0,0, 0, 2, CUR);
  k_gemm<<<128, 256, 0, stream>>>(H, 0, 256,128, 0,0, WtMB1,256,128, nullptr,
                                  Q1f,128,0, 8192, 0,0,0, 0, 2, Q1f);

  // ---- stage 2 ----
  k_gemm<<<128, 256, 0, stream>>>(Q1f, 0, 128,0, alng+384, alnb+384, WtQ2,128,0, abqkv+384,
                                  QPf,128,0, 8192, 0,1,0, 0, 0, nullptr);
  k_gemm<<<512, 256, 0, stream>>>(K1f, 0, 128,0, alng+512, alnb+512, WtK2,128,0, abqkv+512,
                                  KPf,128,0, 33792, 0,1,0, 2, 0, nullptr);
  k_gemm<<<512, 256, 0, stream>>>(V1f, 0, 128,0, alng+640, alnb+640, WtV2,128,0, abqkv+640,
                                  VPf,128,0, 33792, 0,1,0, 2, 0, nullptr);
  k_attn<<<512, 256, 0, stream>>>(QPf, KPf, VPf, AO, 1, 64);
  k_gemm<<<128, 256, 0, stream>>>(AO, 0, 128,0, 0,0, WtP2,128,0, abp+128,
                                  CUR,128,0, 8192, 0,0,0, 0, 2, Q1f);
  k_gemm<<<128, 256, 0, stream>>>(CUR, 0, 128,0, png+128, pnb+128, WtMA2,128,0, bma+256,
                                  H,256,0,   8192, 0,1,1, 0, 0, nullptr);
  k_gemm<<<128, 256, 0, stream>>>(CUR, 0, 128,0, png+128, pnb+128, WtMA2+16384,128,0, bma+384,
                                  H,256,128, 8192, 0,1,1, 0, 0, nullptr);
  k_gemm<<<128, 256, 0, stream>>>(H, 0, 256,0, 0,0, WtMB2,256,0, bmb+128,
                                  Q2f,128,0, 8192, 0,0,0, 0, 2, CUR);
  k_gemm<<<128, 256, 0, stream>>>(H, 0, 256,128, 0,0, WtMB2,256,128, nullptr,
                                  Q2f,128,0, 8192, 0,0,0, 0, 2, Q2f);

  k_final<<<1024, 128, 0, stream>>>(Q2f, postg, postb, out);
}

// Round 3
// 497.191 us; speedup vs baseline: 1.7463x; 1.3394x over previous
//
#include <hip/hip_runtime.h>
#include <math.h>

// CrossViewSwapAttention forward. Round 3: attention on bf16 MFMA too.
// B=2 N=6 H=W=64 FH=32 FW=88 DIM=128 HEADS=4 DH=32 QW=8x8 KW=4x11

typedef __attribute__((ext_vector_type(8))) short short8;
typedef __attribute__((ext_vector_type(4))) float f32x4;

#define LDA 136   // K(=128) + 8 shorts pitch for gemm LDS tiles

__device__ __forceinline__ unsigned short f2bf(float f){
  union { float f; unsigned u; } v; v.f = f;
  unsigned r = v.u + 0x7FFF + ((v.u >> 16) & 1);   // RNE
  return (unsigned short)(r >> 16);
}

__device__ __forceinline__ void store_bf16x8(unsigned short* p, const float* v){
  union { short8 s8; unsigned short u[8]; } u;
  #pragma unroll
  for (int i=0;i<8;i++) u.u[i] = f2bf(v[i]);
  *(short8*)p = u.s8;
}

__device__ __forceinline__ size_t remap_kv(int tok, int mode){
  // tok = bn*2816 + i*88 + j  ->  KP/VP row ((b*64+l)*264 + t)
  int bn = tok / 2816; int p = tok - bn*2816;
  int b = bn / 6, n = bn - b*6;
  int i = p / 88, j = p - i*88;
  int l, t;
  if (mode == 1){            // stage 1: _win(k, 4, 11)
    int jw = j / 11;
    l = (i >> 2)*8 + jw;
    t = n*44 + (i & 3)*11 + (j - jw*11);
  } else {                   // stage 2: _gridwin(k, 4, 11)
    l = (i & 7)*8 + (j & 7);
    t = n*44 + (i >> 3)*11 + (j >> 3);
  }
  return (size_t)((b*64 + l)*264 + t);
}

// c_embed[bn][o] = sum_c W_cam[o][c] * E_inv[bn][c][3]
__global__ __launch_bounds__(128) void k_cembed(const float* __restrict__ Einv,
                                                const float* __restrict__ Wcam,
                                                float* __restrict__ CE){
  int bn = blockIdx.x, o = threadIdx.x;
  const float* E = Einv + bn*16;
  const float* W = Wcam + o*4;
  CE[bn*128 + o] = W[0]*E[3] + W[1]*E[7] + W[2]*E[11] + W[3]*E[15];
}

// one-time weight prep: fp32 [k][n] -> bf16 [n][k] (or straight copy for
// W_fl/W_fp which are already [o][c]=[n][k]).
__global__ __launch_bounds__(256) void k_wprep(const float* __restrict__ qkv,
    const float* __restrict__ wp, const float* __restrict__ wma,
    const float* __restrict__ wmb, const float* __restrict__ wfl,
    const float* __restrict__ wfp, unsigned short* __restrict__ Wt){
  const int sel[14]  = {0,0,0,0,0,0,1,1,2,2,3,3,4,5};
  const int soff[14] = {0,16384,32768,49152,65536,81920,0,16384,0,32768,0,32768,0,0};
  const int doff[14] = {0,16384,32768,49152,65536,81920,98304,114688,131072,163840,196608,229376,262144,278528};
  const int Ks[14]   = {128,128,128,128,128,128,128,128,128,128,256,256,128,128};
  const int Ns[14]   = {128,128,128,128,128,128,128,128,256,256,128,128,128,128};
  const int trs[14]  = {1,1,1,1,1,1,1,1,1,1,1,1,0,0};
  int sg = blockIdx.x >> 2, q = blockIdx.x & 3;
  const float* srcs[6] = {qkv, wp, wma, wmb, wfl, wfp};
  const float* src = srcs[sel[sg]] + soff[sg];
  unsigned short* dst = Wt + doff[sg];
  int K = Ks[sg], N = Ns[sg];
  int quarter = (K*N) >> 2;
  for (int idx = q*quarter + threadIdx.x; idx < (q+1)*quarter; idx += 256){
    int n = idx / K, k = idx - n*K;
    float v = trs[sg] ? src[k*N + n] : src[idx];
    dst[idx] = f2bf(v);
  }
}

// img_embed (normalized over channel) -> K1 (channel-last, (bn,p,c))
__global__ __launch_bounds__(128) void k_geom(const float* __restrict__ Iinv,
                                              const float* __restrict__ Einv,
                                              const float* __restrict__ Wimg,
                                              const float* __restrict__ CE,
                                              float* __restrict__ K1){
  int tile = blockIdx.x;               // bn*352 + tp  (8 pixels per block)
  int bn = tile / 352; int p0 = (tile - bn*352)*8;
  int xid = threadIdx.x >> 4, part = threadIdx.x & 15;
  int p = p0 + xid;
  int i = p / 88, j = p - i*88;
  float xs = (float)j * (480.0f/87.0f);
  float ys = (float)i * (224.0f/31.0f);
  const float* I = Iinv + bn*9;
  const float* E = Einv + bn*16;
  float c0 = I[0]*xs + I[1]*ys + I[2];
  float c1 = I[3]*xs + I[4]*ys + I[5];
  float c2 = I[6]*xs + I[7]*ys + I[8];
  float d0 = E[0]*c0 + E[1]*c1 + E[2]*c2 + E[3];
  float d1 = E[4]*c0 + E[5]*c1 + E[6]*c2 + E[7];
  float d2 = E[8]*c0 + E[9]*c1 + E[10]*c2 + E[11];
  float d3 = E[12]*c0 + E[13]*c1 + E[14]*c2 + E[15];
  float v[8]; float sq = 0.f;
  #pragma unroll
  for (int k=0;k<8;k++){
    int o = part*8 + k;
    const float* W = Wimg + o*4;
    float de = W[0]*d0 + W[1]*d1 + W[2]*d2 + W[3]*d3;
    float vv = de - CE[bn*128 + o];
    v[k] = vv; sq = fmaf(vv, vv, sq);
  }
  #pragma unroll
  for (int off=8; off>0; off>>=1) sq += __shfl_xor(sq, off, 16);
  float rn = 1.0f / fmaxf(sqrtf(sq), 1e-12f);
  float* dst = K1 + (size_t)(bn*2816 + p)*128 + part*8;
  #pragma unroll
  for (int k=0;k<8;k++) dst[k] = v[k]*rn;
}

// query = normalize(w_embed - c_embed) + x, then stage-1 q LayerNorm folded in,
// emitted bf16 in stage-1 window-token order -> feeds MFMA q-gemm directly.
__global__ __launch_bounds__(128) void k_bevq2(const float* __restrict__ gridp,
    const float* __restrict__ Wbev, const float* __restrict__ bbev,
    const float* __restrict__ CE, const float* __restrict__ x,
    const float* __restrict__ lg, const float* __restrict__ lb,
    unsigned short* __restrict__ Qh){
  int tile = blockIdx.x;               // bn*512 + tp (8 pixels per block)
  int bn = tile >> 9; int pp0 = (tile & 511) << 3;
  int b = bn / 6, n = bn - b*6;
  int xid = threadIdx.x >> 4, part = threadIdx.x & 15;
  int pix = pp0 + xid;
  int h = pix >> 6, w = pix & 63;
  float g0 = gridp[pix], g1 = gridp[4096 + pix];
  float v[8]; float sq = 0.f;
  #pragma unroll
  for (int k=0;k<8;k++){
    int o = part*8 + k;
    float we = Wbev[o*2]*g0 + Wbev[o*2+1]*g1 + bbev[o];
    float vv = we - CE[bn*128 + o];
    v[k] = vv; sq = fmaf(vv, vv, sq);
  }
  #pragma unroll
  for (int off=8; off>0; off>>=1) sq += __shfl_xor(sq, off, 16);
  float rn = 1.0f / fmaxf(sqrtf(sq), 1e-12f);
  const float* xp = x + ((size_t)b*128)*4096 + pix;
  float q[8]; float s=0.f, s2=0.f;
  #pragma unroll
  for (int k=0;k<8;k++){
    int o = part*8 + k;
    q[k] = fmaf(v[k], rn, xp[(size_t)o*4096]);
    s += q[k]; s2 = fmaf(q[k], q[k], s2);
  }
  #pragma unroll
  for (int off=8; off>0; off>>=1){ s += __shfl_xor(s, off, 16); s2 += __shfl_xor(s2, off, 16); }
  float mean = s*(1.f/128.f);
  float rstd = rsqrtf(fmaxf(s2*(1.f/128.f) - mean*mean, 0.f) + 1e-5f);
  int l = (h>>3)*8 + (w>>3);
  int t = n*64 + (h&7)*8 + (w&7);
  size_t row = (size_t)((b*64 + l)*384 + t);
  float o8[8];
  #pragma unroll
  for (int k=0;k<8;k++){
    int c = part*8 + k;
    o8[k] = fmaf((q[k]-mean)*rstd, lg[c], lb[c]);
  }
  store_bf16x8(Qh + row*128 + part*8, o8);
}

// Universal MFMA GEMM (K=128, N=128). pre: 0=fp32 rows (+opt LN), 1=conv
// (feat+BN+relu transpose-load), 2=bf16 rows passthrough. Output fp32 (OUT) or
// bf16 (OUTH non-null), optional scale (for softmax-q), gelu, skip, row remap.
__global__ __launch_bounds__(256) void k_gemm(
    const float* __restrict__ Xf, const unsigned short* __restrict__ Xh,
    int ldx, int xoff,
    const float* __restrict__ lg, const float* __restrict__ lb,
    const unsigned short* __restrict__ Wt, int ldw, int woff,
    const float* __restrict__ bias,
    float* __restrict__ OUT, unsigned short* __restrict__ OUTH,
    int ldout, int ooff, float oscale,
    int M, int pre, int do_ln, int act, int outmode, int skip_mode,
    const float* __restrict__ skipp){
  __shared__ unsigned short sA[64*LDA];
  __shared__ unsigned short sW[128*LDA];
  __shared__ float sg[128], sb[128], sbias[128];
  int tid = threadIdx.x;
  for (int i = tid; i < 2048; i += 256){
    int n = i >> 4, k8 = (i & 15) << 3;
    short8 v = *(const short8*)(Wt + (size_t)n*ldw + woff + k8);
    *(short8*)&sW[n*LDA + k8] = v;
  }
  if (tid < 128){
    if (do_ln || pre == 1){ sg[tid] = lg[tid]; sb[tid] = lb[tid]; }
    sbias[tid] = bias ? bias[tid] : 0.f;
  }
  __syncthreads();
  const int lane = tid & 63, wv = tid >> 6;
  const int lane15 = lane & 15, quad = lane >> 4;
  const int n0 = wv * 32;
  const float bs0 = sbias[n0 + lane15], bs1 = sbias[n0 + lane15 + 16];
  const int col0 = n0 + lane15, col1 = col0 + 16;
  const int chunks = M >> 6;
  const float RSQ = rsqrtf(1.0f + 1e-5f);
  for (int ch = blockIdx.x; ch < chunks; ch += gridDim.x){
    int base = ch << 6;
    __syncthreads();
    if (pre == 0){
      int r = tid >> 2, part = tid & 3;
      const float* xp = Xf + (size_t)(base + r)*ldx + xoff + part*32;
      float v[32];
      #pragma unroll
      for (int k=0;k<32;k+=4){
        float4 t4 = *(const float4*)(xp + k);
        v[k]=t4.x; v[k+1]=t4.y; v[k+2]=t4.z; v[k+3]=t4.w;
      }
      if (do_ln){
        float s=0.f, s2=0.f;
        #pragma unroll
        for (int k=0;k<32;k++){ s += v[k]; s2 = fmaf(v[k],v[k],s2); }
        s  += __shfl_xor(s, 2, 4);  s  += __shfl_xor(s, 1, 4);
        s2 += __shfl_xor(s2, 2, 4); s2 += __shfl_xor(s2, 1, 4);
        float mean = s * (1.f/128.f);
        float rstd = rsqrtf(fmaxf(s2*(1.f/128.f) - mean*mean, 0.f) + 1e-5f);
        #pragma unroll
        for (int k=0;k<32;k++){
          int c = part*32 + k;
          v[k] = fmaf((v[k]-mean)*rstd, sg[c], sb[c]);
        }
      }
      unsigned short* ap = sA + r*LDA + part*32;
      store_bf16x8(ap, v); store_bf16x8(ap+8, v+8);
      store_bf16x8(ap+16, v+16); store_bf16x8(ap+24, v+24);
    } else if (pre == 2){
      int r = tid >> 2, part = tid & 3;
      const short8* src = (const short8*)(Xh + (size_t)(base + r)*128 + part*32);
      short8* dst = (short8*)(sA + r*LDA + part*32);
      dst[0]=src[0]; dst[1]=src[1]; dst[2]=src[2]; dst[3]=src[3];
    } else {  // pre == 1
      int prow = tid & 63, cseg = tid >> 6;
      int bn = base / 2816;
      int p = base - bn*2816 + prow;
      const float* fb = Xf + ((size_t)bn*128 + cseg*32)*2816 + p;
      #pragma unroll
      for (int i=0;i<32;i+=2){
        int c = cseg*32 + i;
        float t0 = fb[(size_t)i*2816] * RSQ;
        float t1 = fb[(size_t)(i+1)*2816] * RSQ;
        float y0 = fmaxf(fmaf(t0, sg[c],   sb[c]),   0.f);
        float y1 = fmaxf(fmaf(t1, sg[c+1], sb[c+1]), 0.f);
        unsigned u = (unsigned)f2bf(y0) | ((unsigned)f2bf(y1) << 16);
        *(unsigned*)&sA[prow*LDA + c] = u;
      }
    }
    __syncthreads();
    f32x4 acc[4][2];
    #pragma unroll
    for (int mt=0; mt<4; mt++){ acc[mt][0] = (f32x4)0.f; acc[mt][1] = (f32x4)0.f; }
    const unsigned short* aptr = sA + lane15*LDA + quad*8;
    const unsigned short* bptr = sW + (n0 + lane15)*LDA + quad*8;
    #pragma unroll
    for (int kk=0; kk<4; kk++){
      short8 a0 = *(const short8*)(aptr + kk*32);
      short8 a1 = *(const short8*)(aptr + 16*LDA + kk*32);
      short8 a2 = *(const short8*)(aptr + 32*LDA + kk*32);
      short8 a3 = *(const short8*)(aptr + 48*LDA + kk*32);
      short8 b0 = *(const short8*)(bptr + kk*32);
      short8 b1 = *(const short8*)(bptr + 16*LDA + kk*32);
      acc[0][0] = __builtin_amdgcn_mfma_f32_16x16x32_bf16(a0,b0,acc[0][0],0,0,0);
      acc[1][0] = __builtin_amdgcn_mfma_f32_16x16x32_bf16(a1,b0,acc[1][0],0,0,0);
      acc[2][0] = __builtin_amdgcn_mfma_f32_16x16x32_bf16(a2,b0,acc[2][0],0,0,0);
      acc[3][0] = __builtin_amdgcn_mfma_f32_16x16x32_bf16(a3,b0,acc[3][0],0,0,0);
      acc[0][1] = __builtin_amdgcn_mfma_f32_16x16x32_bf16(a0,b1,acc[0][1],0,0,0);
      acc[1][1] = __builtin_amdgcn_mfma_f32_16x16x32_bf16(a1,b1,acc[1][1],0,0,0);
      acc[2][1] = __builtin_amdgcn_mfma_f32_16x16x32_bf16(a2,b1,acc[2][1],0,0,0);
      acc[3][1] = __builtin_amdgcn_mfma_f32_16x16x32_bf16(a3,b1,acc[3][1],0,0,0);
    }
    #pragma unroll
    for (int mt=0; mt<4; mt++){
      #pragma unroll
      for (int nt=0; nt<2; nt++){
        int col = nt ? col1 : col0;
        float bsv = nt ? bs1 : bs0;
        #pragma unroll
        for (int r4=0; r4<4; r4++){
          int rrow = base + mt*16 + quad*4 + r4;
          float v = acc[mt][nt][r4] + bsv;
          if (act == 1) v = 0.5f*v*(1.f + erff(v*0.70710678118654752f));
          if (skip_mode == 1){
            int bb = rrow >> 12, l = (rrow >> 6) & 63, pp = rrow & 63;
            int pix = (((l>>3)*8 + (pp>>3)) << 6) + (l&7)*8 + (pp&7);
            v += skipp[(size_t)bb*524288 + (size_t)col*4096 + pix];
          } else if (skip_mode == 2){
            v += skipp[(size_t)rrow*128 + col];
          }
          v *= oscale;
          size_t orow = outmode ? remap_kv(rrow, outmode) : (size_t)rrow;
          if (OUTH) OUTH[orow*(size_t)ldout + ooff + col] = f2bf(v);
          else      OUT[orow*(size_t)ldout + ooff + col] = v;
        }
      }
    }
  }
}

// MFMA attention: one block per (b,l,head), 4 waves.
// S^T = K Q^T via mfma (C layout: row=key, col=q) so each lane packs 4
// consecutive-key exp-weights into one ds_write_b64; P re-read in A layout;
// O += P V via mfma with V staged transposed in LDS (B layout n=d, k=key).
// Unnormalized softmax (no max-sub; scores bounded); keys padded 264->288,
// pads masked to e=0. Stage-1: wave w's 6 m-tiles are the 6 cameras of
// pixels w*16..w*16+15 -> camera mean accumulated in-register.
__global__ __launch_bounds__(256) void k_attn2(const unsigned short* __restrict__ QPh,
    const unsigned short* __restrict__ KPh, const unsigned short* __restrict__ VPh,
    unsigned short* __restrict__ AOh, int nrep, int nQ){
  __shared__ unsigned short Ksh[288*40];   // [key][32d + pad]
  __shared__ unsigned short Vt[32*296];    // [d][288key + pad]
  __shared__ unsigned short Psh[4*16*40];  // per-wave P tile [16q][32key + pad]
  __shared__ float rs[4*16];               // per-wave rowsums
  int hd = blockIdx.x & 3; int bl = blockIdx.x >> 2;
  size_t kvbase = (size_t)bl*264;
  int tid = threadIdx.x;
  for (int idx = tid; idx < 1056; idx += 256){     // K: 264 rows x 4 segs
    int row = idx >> 2, seg = idx & 3;
    *(short8*)&Ksh[row*40 + seg*8] =
      *(const short8*)(KPh + (kvbase+row)*128 + hd*32 + seg*8);
  }
  for (int idx = tid; idx < 96; idx += 256){       // zero K pad rows
    int row = 264 + (idx>>2), seg = idx & 3;
    short8 z = {0,0,0,0,0,0,0,0};
    *(short8*)&Ksh[row*40 + seg*8] = z;
  }
  for (int idx = tid; idx < 4224; idx += 256){     // V transpose: 132 kp x 32 d
    int kp = idx >> 5, d = idx & 31;
    unsigned v0 = VPh[(kvbase + 2*kp)*128 + hd*32 + d];
    unsigned v1 = VPh[(kvbase + 2*kp + 1)*128 + hd*32 + d];
    *(unsigned*)&Vt[d*296 + 2*kp] = v0 | (v1 << 16);
  }
  for (int idx = tid; idx < 384; idx += 256){      // zero V pad keys
    int d = idx / 12, kp = 132 + idx % 12;
    *(unsigned*)&Vt[d*296 + 2*kp] = 0u;
  }
  __syncthreads();
  const int wv = tid >> 6, lane = tid & 63;
  const int lane15 = lane & 15, quad = lane >> 4;
  unsigned short* Pw = Psh + wv*640;
  float* rsw = rs + wv*16;
  short8 vfrag[9][2];
  #pragma unroll
  for (int kc=0; kc<9; kc++){
    vfrag[kc][0] = *(const short8*)&Vt[(lane15)*296      + kc*32 + quad*8];
    vfrag[kc][1] = *(const short8*)&Vt[(16+lane15)*296   + kc*32 + quad*8];
  }
  f32x4 macc0 = (f32x4)0.f, macc1 = (f32x4)0.f;
  for (int cam = 0; cam < nrep; cam++){
    int qrow = bl*nQ + (cam*4 + wv)*16 + lane15;
    short8 qf = *(const short8*)(QPh + (size_t)qrow*128 + hd*32 + quad*8);
    f32x4 oa0 = (f32x4)0.f, oa1 = (f32x4)0.f;
    float rsum = 0.f;
    #pragma unroll
    for (int kc=0; kc<9; kc++){
      #pragma unroll
      for (int sub=0; sub<2; sub++){
        int kt = kc*2 + sub;
        short8 kf = *(const short8*)&Ksh[(kt*16 + lane15)*40 + quad*8];
        f32x4 st = __builtin_amdgcn_mfma_f32_16x16x32_bf16(kf, qf, (f32x4)0.f, 0,0,0);
        int kbase = kt*16 + quad*4;
        float e0 = (kbase+0 < 264) ? __expf(st[0]) : 0.f;
        float e1 = (kbase+1 < 264) ? __expf(st[1]) : 0.f;
        float e2 = (kbase+2 < 264) ? __expf(st[2]) : 0.f;
        float e3 = (kbase+3 < 264) ? __expf(st[3]) : 0.f;
        rsum += (e0+e1)+(e2+e3);
        uint2 pk;
        pk.x = (unsigned)f2bf(e0) | ((unsigned)f2bf(e1) << 16);
        pk.y = (unsigned)f2bf(e2) | ((unsigned)f2bf(e3) << 16);
        *(uint2*)&Pw[lane15*40 + sub*16 + quad*4] = pk;
      }
      short8 pf = *(const short8*)&Pw[lane15*40 + quad*8];
      oa0 = __builtin_amdgcn_mfma_f32_16x16x32_bf16(pf, vfrag[kc][0], oa0, 0,0,0);
      oa1 = __builtin_amdgcn_mfma_f32_16x16x32_bf16(pf, vfrag[kc][1], oa1, 0,0,0);
    }
    rsum += __shfl_xor(rsum, 16);
    rsum += __shfl_xor(rsum, 32);
    if (lane < 16) rsw[lane] = rsum;
    f32x4 rv = *(f32x4*)&rsw[quad*4];
    #pragma unroll
    for (int r=0;r<4;r++){
      float inv = 1.f / rv[r];
      macc0[r] = fmaf(oa0[r], inv, macc0[r]);
      macc1[r] = fmaf(oa1[r], inv, macc1[r]);
    }
  }
  float sc = (nrep == 6) ? (1.f/6.f) : 1.f;
  int pixb = wv*16 + quad*4;
  #pragma unroll
  for (int r=0;r<4;r++){
    size_t rowo = ((size_t)(bl*64 + pixb + r))*128 + hd*32;
    AOh[rowo + lane15]      = f2bf(macc0[r]*sc);
    AOh[rowo + 16 + lane15] = f2bf(macc1[r]*sc);
  }
}

// y = x + gelu(LN(x)@Wa + ba)@Wb + bb handled by k_gemm pair; final LN here.
__global__ __launch_bounds__(128) void k_final(const float* __restrict__ X,
    const float* __restrict__ g, const float* __restrict__ be,
    float* __restrict__ out){
  __shared__ float st[1024];
  __shared__ float sm[8], sr[8];
  int r0 = blockIdx.x*8;
  int b = r0 >> 12, l = (r0 >> 6) & 63, p0 = r0 & 63;
  int h = (l >> 3)*8 + (p0 >> 3);
  int wbase = (l & 7)*8;
  for (int idx=threadIdx.x; idx<1024; idx+=128) st[idx] = X[(size_t)r0*128 + idx];
  __syncthreads();
  int xid = threadIdx.x >> 4, part = threadIdx.x & 15;
  float s=0.f, s2=0.f;
  #pragma unroll
  for (int k=0;k<8;k++){
    float v = st[xid*128 + part*8 + k];
    s += v; s2 = fmaf(v,v,s2);
  }
  #pragma unroll
  for (int off=8; off>0; off>>=1){ s += __shfl_xor(s, off, 16); s2 += __shfl_xor(s2, off, 16); }
  if (part == 0){
    float mean = s*(1.f/128.f);
    sm[xid] = mean;
    sr[xid] = rsqrtf(fmaxf(s2*(1.f/128.f) - mean*mean, 0.f) + 1e-5f);
  }
  __syncthreads();
  int o = threadIdx.x;
  float go = g[o], bo = be[o];
  size_t obase = ((size_t)(b*128 + o))*4096 + h*64 + wbase;
  float res[8];
  #pragma unroll
  for (int x=0;x<8;x++) res[x] = fmaf((st[x*128+o]-sm[x])*sr[x], go, bo);
  *(float4*)&out[obase]   = make_float4(res[0],res[1],res[2],res[3]);
  *(float4*)&out[obase+4] = make_float4(res[4],res[5],res[6],res[7]);
}

extern "C" void kernel_launch(void* const* d_in, const int* in_sizes, int n_in,
                              void* d_out, int out_size, void* d_ws, size_t ws_size,
                              hipStream_t stream) {
  (void)in_sizes; (void)n_in; (void)out_size; (void)ws_size;
  const float* x     = (const float*)d_in[1];
  const float* gridp = (const float*)d_in[2];
  const float* feat  = (const float*)d_in[3];
  const float* Iinv  = (const float*)d_in[4];
  const float* Einv  = (const float*)d_in[5];
  const float* gfl   = (const float*)d_in[6];
  const float* bfl   = (const float*)d_in[7];
  const float* Wfl   = (const float*)d_in[8];
  const float* gfp   = (const float*)d_in[9];
  const float* bfp   = (const float*)d_in[10];
  const float* Wfp   = (const float*)d_in[11];
  const float* Wbev  = (const float*)d_in[12];
  const float* bbev  = (const float*)d_in[13];
  const float* Wimg  = (const float*)d_in[14];
  const float* Wcam  = (const float*)d_in[15];
  const float* alng  = (const float*)d_in[16];
  const float* alnb  = (const float*)d_in[17];
  const float* aWqkv = (const float*)d_in[18];
  const float* abqkv = (const float*)d_in[19];
  const float* aWp   = (const float*)d_in[20];
  const float* abp   = (const float*)d_in[21];
  const float* png   = (const float*)d_in[22];
  const float* pnb   = (const float*)d_in[23];
  const float* Wma   = (const float*)d_in[24];
  const float* bma   = (const float*)d_in[25];
  const float* Wmb   = (const float*)d_in[26];
  const float* bmb   = (const float*)d_in[27];
  const float* postg = (const float*)d_in[28];
  const float* postb = (const float*)d_in[29];
  float* out = (float*)d_out;
  float* ws  = (float*)d_ws;
  const float QSC = 0.17677669529663687f;   // 32^-0.5 folded into q projections

  // ws layout (floats), ~90 MB
  float* CE  = ws;                                   // 2048
  unsigned short* Wt = (unsigned short*)(ws + 2048); // 294912 sh = 147456 f
  float* K1f = ws + 149504;                          // 4,325,376
  float* V1f = K1f + 4325376;                        // 4,325,376
  float* KPr = V1f + 4325376;                        // 2,162,688 (bf16 KP) ; H overlays
  float* VPr = KPr + 2162688;                        // 2,162,688 (bf16 VP)
  float* QPr = VPr + 2162688;                        // 3,145,728 (bf16 QP 49152x128)
  float* R   = QPr + 3145728;
  unsigned short* KPh = (unsigned short*)KPr;
  unsigned short* VPh = (unsigned short*)VPr;
  unsigned short* QPh = (unsigned short*)QPr;
  float* H = KPr;                                    // 8192x256 fp32 (2,097,152 f)
  unsigned short* Qbh = (unsigned short*)R;          // 49152x128 bf16 (3,145,728 f)
  unsigned short* AOh = (unsigned short*)R;          // 8192x128 bf16 (overlays Qbh)
  float* CUR = R + 3145728;
  float* Q1f = R + 4194304;
  float* Q2f = R + 5242880;

  unsigned short* WtQ1 = Wt;            unsigned short* WtK1 = Wt + 16384;
  unsigned short* WtV1 = Wt + 32768;    unsigned short* WtQ2 = Wt + 49152;
  unsigned short* WtK2 = Wt + 65536;    unsigned short* WtV2 = Wt + 81920;
  unsigned short* WtP1 = Wt + 98304;    unsigned short* WtP2 = Wt + 114688;
  unsigned short* WtMA1 = Wt + 131072;  unsigned short* WtMA2 = Wt + 163840;
  unsigned short* WtMB1 = Wt + 196608;  unsigned short* WtMB2 = Wt + 229376;
  unsigned short* WtFL = Wt + 262144;   unsigned short* WtFP = Wt + 278528;

  k_cembed<<<12, 128, 0, stream>>>(Einv, Wcam, CE);
  k_wprep<<<56, 256, 0, stream>>>(aWqkv, aWp, Wma, Wmb, Wfl, Wfp, Wt);
  k_geom<<<4224, 128, 0, stream>>>(Iinv, Einv, Wimg, CE, K1f);
  k_bevq2<<<6144, 128, 0, stream>>>(gridp, Wbev, bbev, CE, x, alng, alnb, Qbh);

  // conv: K1 += Wfp@relu(bn(feat)), V1 = Wfl@relu(bn(feat))
  k_gemm<<<512, 256, 0, stream>>>(feat, 0, 0,0, gfp, bfp, WtFP,128,0, nullptr,
                                  K1f, nullptr, 128,0, 1.f, 33792, 1,0,0, 0, 2, K1f);
  k_gemm<<<512, 256, 0, stream>>>(feat, 0, 0,0, gfl, bfl, WtFL,128,0, nullptr,
                                  V1f, nullptr, 128,0, 1.f, 33792, 1,0,0, 0, 0, nullptr);

  // ---- stage 1 ----
  k_gemm<<<512, 256, 0, stream>>>(nullptr, Qbh, 128,0, 0,0, WtQ1,128,0, abqkv,
                                  nullptr, QPh, 128,0, QSC, 49152, 2,0,0, 0, 0, nullptr);
  k_gemm<<<512, 256, 0, stream>>>(K1f, 0, 128,0, alng+128, alnb+128, WtK1,128,0, abqkv+128,
                                  nullptr, KPh, 128,0, 1.f, 33792, 0,1,0, 1, 0, nullptr);
  k_gemm<<<512, 256, 0, stream>>>(V1f, 0, 128,0, alng+256, alnb+256, WtV1,128,0, abqkv+256,
                                  nullptr, VPh, 128,0, 1.f, 33792, 0,1,0, 1, 0, nullptr);
  k_attn2<<<512, 256, 0, stream>>>(QPh, KPh, VPh, AOh, 6, 384);
  k_gemm<<<128, 256, 0, stream>>>(nullptr, AOh, 128,0, 0,0, WtP1,128,0, abp,
                                  CUR, nullptr, 128,0, 1.f, 8192, 2,0,0, 0, 1, x);
  k_gemm<<<128, 256, 0, stream>>>(CUR, 0, 128,0, png, pnb, WtMA1,128,0, bma,
                                  H, nullptr, 256,0, 1.f, 8192, 0,1,1, 0, 0, nullptr);
  k_gemm<<<128, 256, 0, stream>>>(CUR, 0, 128,0, png, pnb, WtMA1+16384,128,0, bma+128,
                                  H, nullptr, 256,128, 1.f, 8192, 0,1,1, 0, 0, nullptr);
  k_gemm<<<128, 256, 0, stream>>>(H, 0, 256,0, 0,0, WtMB1,256,0, bmb,
                                  Q1f, nullptr, 128,0, 1.f, 8192, 0,0,0, 0, 2, CUR);
  k_gemm<<<128, 256, 0, stream>>>(H, 0, 256,128, 0,0, WtMB1,256,128, nullptr,
                                  Q1f, nullptr, 128,0, 1.f, 8192, 0,0,0, 0, 2, Q1f);

  // ---- stage 2 ----
  k_gemm<<<128, 256, 0, stream>>>(Q1f, 0, 128,0, alng+384, alnb+384, WtQ2,128,0, abqkv+384,
                                  nullptr, QPh, 128,0, QSC, 8192, 0,1,0, 0, 0, nullptr);
  k_gemm<<<512, 256, 0, stream>>>(K1f, 0, 128,0, alng+512, alnb+512, WtK2,128,0, abqkv+512,
                                  nullptr, KPh, 128,0, 1.f, 33792, 0,1,0, 2, 0, nullptr);
  k_gemm<<<512, 256, 0, stream>>>(V1f, 0, 128,0, alng+640, alnb+640, WtV2,128,0, abqkv+640,
                                  nullptr, VPh, 128,0, 1.f, 33792, 0,1,0, 2, 0, nullptr);
  k_attn2<<<512, 256, 0, stream>>>(QPh, KPh, VPh, AOh, 1, 64);
  k_gemm<<<128, 256, 0, stream>>>(nullptr, AOh, 128,0, 0,0, WtP2,128,0, abp+128,
                                  CUR, nullptr, 128,0, 1.f, 8192, 2,0,0, 0, 2, Q1f);
  k_gemm<<<128, 256, 0, stream>>>(CUR, 0, 128,0, png+128, pnb+128, WtMA2,128,0, bma+256,
                                  H, nullptr, 256,0, 1.f, 8192, 0,1,1, 0, 0, nullptr);
  k_gemm<<<128, 256, 0, stream>>>(CUR, 0, 128,0, png+128, pnb+128, WtMA2+16384,128,0, bma+384,
                                  H, nullptr, 256,128, 1.f, 8192, 0,1,1, 0, 0, nullptr);
  k_gemm<<<128, 256, 0, stream>>>(H, 0, 256,0, 0,0, WtMB2,256,0, bmb+128,
                                  Q2f, nullptr, 128,0, 1.f, 8192, 0,0,0, 0, 2, CUR);
  k_gemm<<<128, 256, 0, stream>>>(H, 0, 256,128, 0,0, WtMB2,256,128, nullptr,
                                  Q2f, nullptr, 128,0, 1.f, 8192, 0,0,0, 0, 2, Q2f);

  k_final<<<1024, 128, 0, stream>>>(Q2f, postg, postb, out);
}